// Round 5
// baseline (1980.992 us; speedup 1.0000x reference)
//
#include <hip/hip_runtime.h>
#include <math.h>

#define D 768
#define NPROTO 20
#define NCLS 13
#define D4 (D / 4)      // 192 float4 per row
#define NCHUNK 12       // 16 lanes/row, one float4 each -> 12 chunks of 16 float4

__device__ __forceinline__ float dot4f(const float4 a, const float4 b) {
    return a.x * b.x + a.y * b.y + a.z * b.z + a.w * b.w;
}

// 16-lane xor-butterfly: xor1/xor2 as DPP quad_perm (VALU pipe),
// xor4/xor8 as ds_swizzle (only 2 LDS-pipe ops per value).
// Pairing order identical to __shfl_xor s=1,2,4,8 (round-2 numerics).
__device__ __forceinline__ float red16(float v) {
    v += __int_as_float(__builtin_amdgcn_update_dpp(
        0, __float_as_int(v), 0xB1, 0xF, 0xF, true));   // xor 1
    v += __int_as_float(__builtin_amdgcn_update_dpp(
        0, __float_as_int(v), 0x4E, 0xF, 0xF, true));   // xor 2
    v += __shfl_xor(v, 4, 64);
    v += __shfl_xor(v, 8, 64);
    return v;
}

// ws layout (floats): [0, 15360) protos_norm [20][768]; [15360, 15620) logits [20][13]

// One block per prototype. Numerics identical to rounds 1-4 (passed) prep.
__global__ __launch_bounds__(256) void proto_prep(
    const float* __restrict__ prototypes,
    const int* __restrict__ role_id,
    const float* __restrict__ W,
    const float* __restrict__ bvec,
    float* __restrict__ ws)
{
    const int p = blockIdx.x;            // 0..19
    const int tid = threadIdx.x;
    const int wave = tid >> 6;
    const int lane = tid & 63;

    const float4* src = reinterpret_cast<const float4*>(
        prototypes + ((size_t)role_id[0] * NPROTO + p) * D);
    float4 v[3];
    #pragma unroll
    for (int j = 0; j < 3; ++j) v[j] = src[lane + 64 * j];

    float ss = 0.f;
    #pragma unroll
    for (int j = 0; j < 3; ++j) ss += dot4f(v[j], v[j]);
    #pragma unroll
    for (int s = 1; s < 64; s <<= 1) ss += __shfl_xor(ss, s, 64);
    const float nrm = fmaxf(sqrtf(ss), 1e-12f);

    float4 nv[3];
    #pragma unroll
    for (int j = 0; j < 3; ++j) {
        nv[j].x = v[j].x / nrm; nv[j].y = v[j].y / nrm;
        nv[j].z = v[j].z / nrm; nv[j].w = v[j].w / nrm;
    }
    if (wave == 0) {
        float4* dst = reinterpret_cast<float4*>(ws + (size_t)p * D);
        #pragma unroll
        for (int j = 0; j < 3; ++j) dst[lane + 64 * j] = nv[j];
    }

    for (int r = wave; r < NCLS; r += 4) {
        const float4* wr = reinterpret_cast<const float4*>(W + (size_t)r * D);
        float a = 0.f;
        #pragma unroll
        for (int j = 0; j < 3; ++j) a += dot4f(nv[j], wr[lane + 64 * j]);
        #pragma unroll
        for (int s = 1; s < 64; s <<= 1) a += __shfl_xor(a, s, 64);
        if (lane == 0) ws[NPROTO * D + p * NCLS + r] = a + bvec[r];
    }
}

// 16 lanes per row-group, 4 rows per group -> 16 rows/wave, 64 rows/block.
// Global x loads: 256 B contiguous per row per instruction (full cache lines).
// Proto LDS reads: 256 B unique per instr, 4-way broadcast, 2-way banks (free).
// 2-chunk-deep rotating prefetch (3 buffers, static indexing).
__global__ __launch_bounds__(256, 2) void proto_main(
    const float* __restrict__ x,
    const float* __restrict__ ws,
    float* __restrict__ out_min,
    float* __restrict__ out_pred)
{
    __shared__ float pl[NPROTO * D];        // 61440 B
    __shared__ float lgs[NPROTO * NCLS];    // 1040 B
    const int tid = threadIdx.x;

    {
        const float4* src = reinterpret_cast<const float4*>(ws);
        float4* dst = reinterpret_cast<float4*>(pl);
        #pragma unroll
        for (int k = 0; k < 15; ++k) dst[tid + 256 * k] = src[tid + 256 * k];
        lgs[tid] = ws[NPROTO * D + tid];
        if (tid < NPROTO * NCLS - 256) lgs[256 + tid] = ws[NPROTO * D + 256 + tid];
    }
    __syncthreads();

    const int wave = tid >> 6;
    const int lane = tid & 63;
    const int g   = lane >> 4;      // row group within wave (4 rows each)
    const int sub = lane & 15;      // float4 slot within a 16-float4 chunk
    const int row0 = blockIdx.x * 64 + wave * 16 + g * 4;

    const float4* xr0 = reinterpret_cast<const float4*>(x + (size_t)(row0 + 0) * D) + sub;
    const float4* xr1 = reinterpret_cast<const float4*>(x + (size_t)(row0 + 1) * D) + sub;
    const float4* xr2 = reinterpret_cast<const float4*>(x + (size_t)(row0 + 2) * D) + sub;
    const float4* xr3 = reinterpret_cast<const float4*>(x + (size_t)(row0 + 3) * D) + sub;
    const float4* pl4 = reinterpret_cast<const float4*>(pl);

    float acc[NPROTO][4];
    #pragma unroll
    for (int p = 0; p < NPROTO; ++p) {
        #pragma unroll
        for (int r = 0; r < 4; ++r) acc[p][r] = 0.f;
    }
    float ssx[4] = {0.f, 0.f, 0.f, 0.f};

    float4 bufA[4], bufB[4], bufC[4];

#define LOADX(BUF, J) do {                          \
        bufA[0] = bufA[0]; /* no-op anchor */       \
        (BUF)[0] = xr0[16 * (J)];                   \
        (BUF)[1] = xr1[16 * (J)];                   \
        (BUF)[2] = xr2[16 * (J)];                   \
        (BUF)[3] = xr3[16 * (J)];                   \
    } while (0)

#define COMPUTE(BUF, J) do {                                        \
        const float4* pp = pl4 + 16 * (J) + sub;                    \
        _Pragma("unroll")                                           \
        for (int p = 0; p < NPROTO; ++p) {                          \
            const float4 pv = pp[p * D4];                           \
            _Pragma("unroll")                                       \
            for (int r = 0; r < 4; ++r)                             \
                acc[p][r] += dot4f((BUF)[r], pv);                   \
        }                                                           \
        _Pragma("unroll")                                           \
        for (int r = 0; r < 4; ++r)                                 \
            ssx[r] += dot4f((BUF)[r], (BUF)[r]);                    \
    } while (0)

    LOADX(bufA, 0);
    LOADX(bufB, 1);

    #pragma unroll
    for (int t = 0; t < 4; ++t) {
        const int j = 3 * t;
        LOADX(bufC, j + 2);                 // j+2 <= 11 always
        COMPUTE(bufA, j);
        if (j + 3 < NCHUNK) LOADX(bufA, j + 3);
        COMPUTE(bufB, j + 1);
        if (j + 4 < NCHUNK) LOADX(bufB, j + 4);
        COMPUTE(bufC, j + 2);
    }

#undef LOADX
#undef COMPUTE

    #pragma unroll
    for (int r = 0; r < 4; ++r) {
        const float ss = red16(ssx[r]);
        const float inv = 1.0f / fmaxf(sqrtf(ss), 1e-12f);

        // np-order scan in dist space (strict > keeps first index on ties)
        float best = 0.f; int bidx = 0;
        #pragma unroll
        for (int p = 0; p < NPROTO; ++p) {
            const float sim = red16(acc[p][r]) * inv;
            const float u = expf(sim) / 10.0f;
            const float dcur = 1.0f / (1.0f + u);
            if (p == 0) best = dcur;
            else if (dcur > best) { best = dcur; bidx = p; }
        }

        const int row = row0 + r;
        if (sub == 0) out_min[row] = best;
        if (sub < NCLS) out_pred[(size_t)row * NCLS + sub] = lgs[bidx * NCLS + sub];
    }
}

extern "C" void kernel_launch(void* const* d_in, const int* in_sizes, int n_in,
                              void* d_out, int out_size, void* d_ws, size_t ws_size,
                              hipStream_t stream) {
    const float* x          = (const float*)d_in[0];   // [B, 768]
    const int*   role_id    = (const int*)d_in[1];     // scalar
    const float* prototypes = (const float*)d_in[2];   // [260, 768]
    const float* W          = (const float*)d_in[3];   // [13, 768]
    const float* b          = (const float*)d_in[4];   // [13]
    float* out = (float*)d_out;
    float* ws  = (float*)d_ws;

    const int B = in_sizes[0] / D;                     // 131072

    proto_prep<<<NPROTO, 256, 0, stream>>>(prototypes, role_id, W, b, ws);
    proto_main<<<B / 64, 256, 0, stream>>>(x, ws, out, out + B);
}

// Round 8
// 1825.106 us; speedup vs baseline: 1.0854x; 1.0854x over previous
//
#include <hip/hip_runtime.h>
#include <math.h>

#define D 768
#define NPROTO 20
#define NCLS 13
#define D4 (D / 4)      // 192 float4 per row
#define NCHUNK 12       // 16 lanes/row, one float4 each -> 12 chunks

__device__ __forceinline__ float dot4f(const float4 a, const float4 b) {
    return a.x * b.x + a.y * b.y + a.z * b.z + a.w * b.w;
}

template <int CTRL>
__device__ __forceinline__ float dpp_mov(float v) {
    return __int_as_float(__builtin_amdgcn_update_dpp(
        0, __float_as_int(v), CTRL, 0xF, 0xF, true));
}

// 16-lane butterfly, bit-identical pairing to __shfl_xor s=1,2,4,8,
// entirely on the VALU pipe (DPP), zero LDS ops.
// Direction ground truth (AMD GCN scan idiom): row_shr:N => lane i <- i-N,
//                                              row_shl:N => lane i <- i+N.
__device__ __forceinline__ float red16(float v, bool hi4) {
    v += dpp_mov<0xB1>(v);                 // quad_perm [1,0,3,2]  == xor 1
    v += dpp_mov<0x4E>(v);                 // quad_perm [2,3,0,1]  == xor 2
    const float up   = dpp_mov<0x114>(v);  // row_shr:4 : lane i <- i-4
    const float down = dpp_mov<0x104>(v);  // row_shl:4 : lane i <- i+4
    v += hi4 ? up : down;                  // exact partner lane^4, in-bounds
    v += dpp_mov<0x128>(v);                // row_ror:8 == xor 8 within 16
    return v;
}

// ws layout (floats): [0, 15360) protos_norm [20][768]; [15360, 15620) logits [20][13]

// One block per prototype. Numerics identical to rounds 1-5 (passed) prep.
__global__ __launch_bounds__(256) void proto_prep(
    const float* __restrict__ prototypes,
    const int* __restrict__ role_id,
    const float* __restrict__ W,
    const float* __restrict__ bvec,
    float* __restrict__ ws)
{
    const int p = blockIdx.x;            // 0..19
    const int tid = threadIdx.x;
    const int wave = tid >> 6;
    const int lane = tid & 63;

    const float4* src = reinterpret_cast<const float4*>(
        prototypes + ((size_t)role_id[0] * NPROTO + p) * D);
    float4 v[3];
    #pragma unroll
    for (int j = 0; j < 3; ++j) v[j] = src[lane + 64 * j];

    float ss = 0.f;
    #pragma unroll
    for (int j = 0; j < 3; ++j) ss += dot4f(v[j], v[j]);
    #pragma unroll
    for (int s = 1; s < 64; s <<= 1) ss += __shfl_xor(ss, s, 64);
    const float nrm = fmaxf(sqrtf(ss), 1e-12f);

    float4 nv[3];
    #pragma unroll
    for (int j = 0; j < 3; ++j) {
        nv[j].x = v[j].x / nrm; nv[j].y = v[j].y / nrm;
        nv[j].z = v[j].z / nrm; nv[j].w = v[j].w / nrm;
    }
    if (wave == 0) {
        float4* dst = reinterpret_cast<float4*>(ws + (size_t)p * D);
        #pragma unroll
        for (int j = 0; j < 3; ++j) dst[lane + 64 * j] = nv[j];
    }

    for (int r = wave; r < NCLS; r += 4) {
        const float4* wr = reinterpret_cast<const float4*>(W + (size_t)r * D);
        float a = 0.f;
        #pragma unroll
        for (int j = 0; j < 3; ++j) a += dot4f(nv[j], wr[lane + 64 * j]);
        #pragma unroll
        for (int s = 1; s < 64; s <<= 1) a += __shfl_xor(a, s, 64);
        if (lane == 0) ws[NPROTO * D + p * NCLS + r] = a + bvec[r];
    }
}

// 512-thread blocks: 61.4 KB LDS amortized over 8 waves -> 2 blocks/CU
// = 16 waves/CU = 4 waves/SIMD. 16 lanes/row, 2 rows/group, acc[20][2]=40
// VGPR; depth-2 prefetch via 3 statically-indexed buffers. VGPR cap 128.
__global__ __launch_bounds__(512, 2) void proto_main(
    const float* __restrict__ x,
    const float* __restrict__ ws,
    float* __restrict__ out_min,
    float* __restrict__ out_pred)
{
    __shared__ float pl[NPROTO * D];        // 61440 B
    __shared__ float lgs[NPROTO * NCLS];    // 1040 B
    const int tid = threadIdx.x;

    {   // stage 3840 float4 of protos + 260 logits
        const float4* src = reinterpret_cast<const float4*>(ws);
        float4* dst = reinterpret_cast<float4*>(pl);
        #pragma unroll
        for (int k = 0; k < 7; ++k) dst[tid + 512 * k] = src[tid + 512 * k];
        if (tid < 3840 - 3584) dst[3584 + tid] = src[3584 + tid];
        if (tid < NPROTO * NCLS) lgs[tid] = ws[NPROTO * D + tid];
    }
    __syncthreads();

    const int wave = tid >> 6;      // 0..7
    const int lane = tid & 63;
    const int g   = lane >> 4;      // row group within wave (2 rows each)
    const int sub = lane & 15;      // float4 slot within a 16-float4 chunk
    const bool hi4 = (lane & 4) != 0;
    const int row0 = blockIdx.x * 64 + wave * 8 + g * 2;

    const float4* xr0 = reinterpret_cast<const float4*>(x + (size_t)(row0 + 0) * D) + sub;
    const float4* xr1 = reinterpret_cast<const float4*>(x + (size_t)(row0 + 1) * D) + sub;
    const float4* pl4 = reinterpret_cast<const float4*>(pl);

    float acc[NPROTO][2];
    #pragma unroll
    for (int p = 0; p < NPROTO; ++p) { acc[p][0] = 0.f; acc[p][1] = 0.f; }
    float ssx[2] = {0.f, 0.f};

    float4 xb[3][2];                // rotating prefetch, all indices static
    xb[0][0] = xr0[0];  xb[0][1] = xr1[0];
    xb[1][0] = xr0[16]; xb[1][1] = xr1[16];

    #pragma unroll
    for (int j = 0; j < NCHUNK; ++j) {
        if (j + 2 < NCHUNK) {
            xb[(j + 2) % 3][0] = xr0[16 * (j + 2)];
            xb[(j + 2) % 3][1] = xr1[16 * (j + 2)];
        }
        const float4 x0 = xb[j % 3][0];
        const float4 x1 = xb[j % 3][1];
        const float4* pp = pl4 + 16 * j + sub;
        #pragma unroll
        for (int p = 0; p < NPROTO; ++p) {
            const float4 pv = pp[p * D4];
            acc[p][0] += dot4f(x0, pv);
            acc[p][1] += dot4f(x1, pv);
        }
        ssx[0] += dot4f(x0, x0);
        ssx[1] += dot4f(x1, x1);
    }

    #pragma unroll
    for (int r = 0; r < 2; ++r) {
        const float ss = red16(ssx[r], hi4);
        const float inv = 1.0f / fmaxf(sqrtf(ss), 1e-12f);

        // np-order scan in dist space (strict > keeps first index on ties)
        float best = 0.f; int bidx = 0;
        #pragma unroll
        for (int p = 0; p < NPROTO; ++p) {
            const float sim = red16(acc[p][r], hi4) * inv;
            const float u = expf(sim) / 10.0f;
            const float dcur = 1.0f / (1.0f + u);
            if (p == 0) best = dcur;
            else if (dcur > best) { best = dcur; bidx = p; }
        }

        const int row = row0 + r;
        if (sub == 0) out_min[row] = best;
        if (sub < NCLS) out_pred[(size_t)row * NCLS + sub] = lgs[bidx * NCLS + sub];
    }
}

extern "C" void kernel_launch(void* const* d_in, const int* in_sizes, int n_in,
                              void* d_out, int out_size, void* d_ws, size_t ws_size,
                              hipStream_t stream) {
    const float* x          = (const float*)d_in[0];   // [B, 768]
    const int*   role_id    = (const int*)d_in[1];     // scalar
    const float* prototypes = (const float*)d_in[2];   // [260, 768]
    const float* W          = (const float*)d_in[3];   // [13, 768]
    const float* b          = (const float*)d_in[4];   // [13]
    float* out = (float*)d_out;
    float* ws  = (float*)d_ws;

    const int B = in_sizes[0] / D;                     // 131072

    proto_prep<<<NPROTO, 256, 0, stream>>>(prototypes, role_id, W, b, ws);
    proto_main<<<B / 64, 512, 0, stream>>>(x, ws, out, out + B);
}